// Round 7
// baseline (2043.474 us; speedup 1.0000x reference)
//
#include <hip/hip_runtime.h>

#define BB 16
#define NN 2048
#define MM 2048
#define EPSF 1e-9f

constexpr int CHC = 256;   // i-chunk length (colA)  -> grid 16*8*8 = 1024
constexpr int CHR = 256;   // l-chunk length (rowA)  -> grid 1024

// Workspace:
//  P1[b*NN+i] = float4(x1,y1,z1, scale_i)   -- scale written by rowA finalize
//  P2[b*MM+l] = float4(x2,y2,z2, remR_l)    -- remR updated by colA finalize
//  remL[b*NN+i]
//  Pcol[b*MM+l] = remR_l*cons_l             -- written by colA finalize
//  stS/stT[b*MM+l], stRS/stU[b*NN+i]        -- partials (reset by finalizers)
//  cntC[b*8+cg], cntR[b*8+rg]               -- arrival counters (reset by finalizers)

// ---------------- init ----------------
__global__ __launch_bounds__(256) void init_kernel(
    const float* __restrict__ xyz1, const float* __restrict__ xyz2,
    float4* __restrict__ P1, float4* __restrict__ P2,
    float* __restrict__ remL,
    float* __restrict__ stS, float* __restrict__ stT,
    float* __restrict__ stRS, float* __restrict__ stU,
    int* __restrict__ cntC, int* __restrict__ cntR,
    float* __restrict__ out)
{
    const int t = blockIdx.x * 256 + threadIdx.x;
    if (t < BB * NN) {
        P1[t] = make_float4(xyz1[3*t+0], xyz1[3*t+1], xyz1[3*t+2], 0.0f);
        remL[t] = 1.0f;
        stRS[t] = 0.0f; stU[t] = 0.0f;
    }
    if (t < BB * MM) {
        P2[t] = make_float4(xyz2[3*t+0], xyz2[3*t+1], xyz2[3*t+2], 1.0f); // .w = remR
        stS[t] = 0.0f; stT[t] = 0.0f;
    }
    if (t < BB * 8) { cntC[t] = 0; cntR[t] = 0; }
    if (t < BB) out[t] = 0.0f;
}

// ---------------- colA: partial s,t + last-arriver finalize ----------------
__global__ __launch_bounds__(256) void colA(
    const float4* __restrict__ P1, float4* __restrict__ P2,
    float* __restrict__ Pcol,
    float* __restrict__ stS, float* __restrict__ stT,
    int* __restrict__ cntC, float* __restrict__ out, float coef)
{
    const int chunks = NN / CHC;                  // 8
    const int bpbatch = (MM / 256) * chunks;      // 64
    const int batch = blockIdx.x / bpbatch;
    const int rem   = blockIdx.x % bpbatch;
    const int cg    = rem / chunks;               // 256-col group 0..7
    const int ic    = rem % chunks;               // i-chunk
    const int col   = batch * MM + cg * 256 + threadIdx.x;

    const float4 q = P2[col];
    const float qx = q.x, qy = q.y, qz = q.z;
    const float4* __restrict__ p1 = P1 + batch * NN + ic * CHC;

    float s = 0.0f, t = 0.0f;
#pragma unroll 4
    for (int ii = 0; ii < CHC; ++ii) {
        const float4 a = p1[ii];                  // wave-uniform stream
        const float dx = a.x - qx, dy = a.y - qy, dz = a.z - qz;
        const float d2 = dx*dx + dy*dy + dz*dz;
        const float se = a.w * __builtin_amdgcn_exp2f(coef * d2);
        s += se;
        t = fmaf(se, __builtin_amdgcn_sqrtf(d2), t);
    }
    atomicAdd(&stS[col], s);
    atomicAdd(&stT[col], t);

    __shared__ int isLast;
    __syncthreads();                              // drains vmcnt: block's atomics issued
    if (threadIdx.x == 0) {
        __threadfence();
        const int old = __hip_atomic_fetch_add(&cntC[batch * 8 + cg], 1,
                          __ATOMIC_ACQ_REL, __HIP_MEMORY_SCOPE_AGENT);
        isLast = (old == chunks - 1) ? 1 : 0;
    }
    __syncthreads();
    if (!isLast) return;

    // ---- finalize (one thread per column) ----
    __threadfence();
    const float ss = __hip_atomic_load(&stS[col], __ATOMIC_RELAXED, __HIP_MEMORY_SCOPE_AGENT);
    const float tt = __hip_atomic_load(&stT[col], __ATOMIC_RELAXED, __HIP_MEMORY_SCOPE_AGENT);
    __hip_atomic_store(&stS[col], 0.0f, __ATOMIC_RELAXED, __HIP_MEMORY_SCOPE_AGENT);
    __hip_atomic_store(&stT[col], 0.0f, __ATOMIC_RELAXED, __HIP_MEMORY_SCOPE_AGENT);
    float* p2w = (float*)P2;
    const float R = p2w[4 * col + 3];
    const float sumr = ss * R;
    const float cons = fminf(R / (sumr + EPSF), 1.0f);
    Pcol[col] = R * cons;
    p2w[4 * col + 3] = fmaxf(R - sumr * cons, 0.0f);
    if (threadIdx.x == 0)
        __hip_atomic_store(&cntC[batch * 8 + cg], 0, __ATOMIC_RELAXED, __HIP_MEMORY_SCOPE_AGENT);
    float c = R * cons * tt;
#pragma unroll
    for (int off = 32; off > 0; off >>= 1) c += __shfl_xor(c, off, 64);
    if ((threadIdx.x & 63) == 0) atomicAdd(out + batch, c);
}

// ---------------- rowA: partial rs,u + last-arriver finalize ----------------
// MODE 0: rs at coefNext only (first pass, remL==1, no u).
// MODE 1: u at level j via e_next^4, rs at level j+1 (coefNext).
// MODE 2: u at coefPrev direct, rs = sum(Rn) (level 0 => e_next=1).
template<int MODE>
__global__ __launch_bounds__(256) void rowA(
    float4* __restrict__ P2, const float* __restrict__ Pcol,
    float4* __restrict__ P1, float* __restrict__ remL,
    float* __restrict__ stRS, float* __restrict__ stU,
    int* __restrict__ cntR,
    float coefPrev, float coefNext)
{
    const int chunks = MM / CHR;                  // 8
    const int bpbatch = (NN / 256) * chunks;      // 64
    const int batch = blockIdx.x / bpbatch;
    const int rem   = blockIdx.x % bpbatch;
    const int rg    = rem / chunks;               // 256-row group 0..7
    const int ic    = rem % chunks;               // l-chunk
    const int row   = batch * NN + rg * 256 + threadIdx.x;

    const float4 p = P1[row];
    const float px = p.x, py = p.y, pz = p.z;
    const float4* __restrict__ p2 = P2 + batch * MM + ic * CHR;
    const float* __restrict__ pc  = Pcol + batch * MM + ic * CHR;

    float rs = 0.0f, u = 0.0f;
#pragma unroll 4
    for (int ii = 0; ii < CHR; ++ii) {
        const float4 q = p2[ii];                  // wave-uniform stream
        const float dx = px - q.x, dy = py - q.y, dz = pz - q.z;
        const float d2 = dx*dx + dy*dy + dz*dz;
        if (MODE == 0) {
            rs = fmaf(__builtin_amdgcn_exp2f(coefNext * d2), q.w, rs);
        } else if (MODE == 1) {
            const float en = __builtin_amdgcn_exp2f(coefNext * d2);
            const float e2 = en * en;
            u  = fmaf(e2 * e2, pc[ii], u);        // e_prev = e_next^4
            rs = fmaf(en, q.w, rs);
        } else {
            const float ep = __builtin_amdgcn_exp2f(coefPrev * d2);
            u  = fmaf(ep, pc[ii], u);
            rs += q.w;                            // e_next = 1
        }
    }
    atomicAdd(&stRS[row], rs);
    if (MODE != 0) atomicAdd(&stU[row], u);

    __shared__ int isLast;
    __syncthreads();
    if (threadIdx.x == 0) {
        __threadfence();
        const int old = __hip_atomic_fetch_add(&cntR[batch * 8 + rg], 1,
                          __ATOMIC_ACQ_REL, __HIP_MEMORY_SCOPE_AGENT);
        isLast = (old == chunks - 1) ? 1 : 0;
    }
    __syncthreads();
    if (!isLast) return;

    // ---- finalize (one thread per row) ----
    __threadfence();
    const float rsum = __hip_atomic_load(&stRS[row], __ATOMIC_RELAXED, __HIP_MEMORY_SCOPE_AGENT);
    __hip_atomic_store(&stRS[row], 0.0f, __ATOMIC_RELAXED, __HIP_MEMORY_SCOPE_AGENT);
    float* p1w = (float*)P1;
    float L;
    if (MODE == 0) {
        L = 1.0f;                                 // initial remL
    } else {
        const float uu = __hip_atomic_load(&stU[row], __ATOMIC_RELAXED, __HIP_MEMORY_SCOPE_AGENT);
        __hip_atomic_store(&stU[row], 0.0f, __ATOMIC_RELAXED, __HIP_MEMORY_SCOPE_AGENT);
        L = fmaxf(remL[row] - p1w[4 * row + 3] * uu, 0.0f);
        remL[row] = L;
    }
    p1w[4 * row + 3] = L / (rsum + EPSF);         // scale
    if (threadIdx.x == 0)
        __hip_atomic_store(&cntR[batch * 8 + rg], 0, __ATOMIC_RELAXED, __HIP_MEMORY_SCOPE_AGENT);
}

extern "C" void kernel_launch(void* const* d_in, const int* in_sizes, int n_in,
                              void* d_out, int out_size, void* d_ws, size_t ws_size,
                              hipStream_t stream)
{
    const float* xyz1 = (const float*)d_in[0];
    const float* xyz2 = (const float*)d_in[1];
    float* out = (float*)d_out;

    const int BN = BB * NN, BM = BB * MM;
    float4* P1 = (float4*)d_ws;
    float4* P2 = P1 + BN;
    float*  remL = (float*)(P2 + BM);
    float*  Pcol = remL + BN;
    float*  stS  = Pcol + BM;
    float*  stT  = stS + BM;
    float*  stRS = stT + BM;
    float*  stU  = stRS + BN;
    int*    cntC = (int*)(stU + BN);
    int*    cntR = cntC + BB * 8;

    init_kernel<<<dim3((BN + 255) / 256), dim3(256), 0, stream>>>(
        xyz1, xyz2, P1, P2, remL, stS, stT, stRS, stU, cntC, cntR, out);

    // levels: j = 7..-1 -> -(4^j), then 0.  coef = level * log2(e)
    float coef[10];
    const double lv[10] = {-16384.0, -4096.0, -1024.0, -256.0, -64.0,
                           -16.0, -4.0, -1.0, -0.25, 0.0};
    for (int i = 0; i < 10; ++i) coef[i] = (float)(lv[i] * 1.4426950408889634);

    dim3 agrid(BB * (MM / 256) * (NN / CHC));        // 1024
    dim3 rgrid(BB * (NN / 256) * (MM / CHR));        // 1024
    dim3 blk(256);

    rowA<0><<<rgrid, blk, 0, stream>>>(P2, Pcol, P1, remL, stRS, stU, cntR, 0.0f, coef[0]);
    for (int j = 0; j < 10; ++j) {
        colA<<<agrid, blk, 0, stream>>>(P1, P2, Pcol, stS, stT, cntC, out, coef[j]);
        if (j < 8) {
            rowA<1><<<rgrid, blk, 0, stream>>>(P2, Pcol, P1, remL, stRS, stU, cntR,
                                               coef[j], coef[j+1]);
        } else if (j == 8) {
            rowA<2><<<rgrid, blk, 0, stream>>>(P2, Pcol, P1, remL, stRS, stU, cntR,
                                               coef[8], 0.0f);
        }
    }
}

// Round 8
// 614.043 us; speedup vs baseline: 3.3279x; 3.3279x over previous
//
#include <hip/hip_runtime.h>

#define BB 16
#define NN 2048
#define MM 2048
#define EPSF 1e-9f

constexpr int CH = 128;    // stream chunk length

// Ping-pong state (all cross-kernel comms at dispatch boundaries; duplicate
// writers always write bit-identical values):
//  P1/P2: packed xyz (w unused)
//  remL[2], scale[2] (per-row), remR[2] (per-col)
//  stRS[2], stU[2] (row partials), stS[2], stT[2] (col partials)
// Parity rules (j = level):
//  colK(j): reads remL/scale[j%2], writes [1-j%2]; reads stRS/stU[1-j%2],
//           zeroes stRS/stU[j%2]; accumulates stS/stT[j%2]
//  rowK(j): reads stS/stT[j%2], zeroes [1-j%2]; reads remR[j%2], writes [1-j%2];
//           accumulates stRS/stU[j%2]
//  rowInit accumulates stRS[1]; init writes remR[0]=1, zeroes all partials.

// ---------------- init ----------------
__global__ __launch_bounds__(256) void init_kernel(
    const float* __restrict__ xyz1, const float* __restrict__ xyz2,
    float4* __restrict__ P1, float4* __restrict__ P2,
    float* __restrict__ remR0,
    float* __restrict__ stRS, float* __restrict__ stU,
    float* __restrict__ stS, float* __restrict__ stT,
    float* __restrict__ out)
{
    const int t = blockIdx.x * 256 + threadIdx.x;   // 0 .. BB*NN-1
    if (t < BB * NN) {
        P1[t] = make_float4(xyz1[3*t+0], xyz1[3*t+1], xyz1[3*t+2], 0.0f);
        stRS[t] = 0.0f; stRS[BB*NN + t] = 0.0f;
        stU[t]  = 0.0f; stU[BB*NN + t]  = 0.0f;
    }
    if (t < BB * MM) {
        P2[t] = make_float4(xyz2[3*t+0], xyz2[3*t+1], xyz2[3*t+2], 0.0f);
        remR0[t] = 1.0f;
        stS[t] = 0.0f; stS[BB*MM + t] = 0.0f;
        stT[t] = 0.0f; stT[BB*MM + t] = 0.0f;
    }
    if (t < BB) out[t] = 0.0f;
}

// ---------------- rowInit: stRS[1] = sum_l exp(coef0*d2) (remR=1) ----------------
__global__ __launch_bounds__(256) void rowInit(
    const float4* __restrict__ P1, const float4* __restrict__ P2,
    float* __restrict__ stRSacc, float coef)
{
    __shared__ float4 sCol[CH];
    const int chunks = MM / CH;                   // 16
    const int bpb = (NN / 256) * chunks;          // 128
    const int batch = blockIdx.x / bpb;
    const int rem   = blockIdx.x % bpb;
    const int rg    = rem / chunks;
    const int ic    = rem % chunks;
    const int t     = threadIdx.x;

    if (t < CH) sCol[t] = P2[batch * MM + ic * CH + t];
    __syncthreads();

    const float4 p = P1[batch * NN + rg * 256 + t];
    float rs = 0.0f;
#pragma unroll 8
    for (int ii = 0; ii < CH; ++ii) {
        const float4 q = sCol[ii];
        const float dx = p.x - q.x, dy = p.y - q.y, dz = p.z - q.z;
        rs += __builtin_amdgcn_exp2f(coef * (dx*dx + dy*dy + dz*dz));
    }
    atomicAdd(&stRSacc[batch * NN + rg * 256 + t], rs);
}

// ---------------- colK: row-finalize prelude + column-partial stream ----------------
// MODE 0: j==0 (remL=1, no u/scale read). MODE 1: general. MODE 2: j==9 (coef==0 -> e=1).
template<int MODE>
__global__ __launch_bounds__(256) void colK(
    const float4* __restrict__ P1, const float4* __restrict__ P2,
    const float* __restrict__ stRSr, const float* __restrict__ stUr,
    float* __restrict__ stRSz, float* __restrict__ stUz,
    const float* __restrict__ remLr, float* __restrict__ remLw,
    const float* __restrict__ scaler, float* __restrict__ scalew,
    float* __restrict__ stS, float* __restrict__ stT,
    float coef)
{
    __shared__ float4 sRow[CH];                   // x1,y1,z1,scale_j
    const int chunks = NN / CH;                   // 16
    const int bpb = (MM / 256) * chunks;          // 128
    const int batch = blockIdx.x / bpb;
    const int rem   = blockIdx.x % bpb;
    const int cg    = rem / chunks;
    const int ic    = rem % chunks;
    const int t     = threadIdx.x;

    // prelude: finalize rows of this chunk (duplicated by 8 cg-blocks; identical values)
    if (t < CH) {
        const int gi = batch * NN + ic * CH + t;
        float L;
        if (MODE == 0) L = 1.0f;
        else           L = fmaxf(remLr[gi] - scaler[gi] * stUr[gi], 0.0f);
        remLw[gi] = L;
        const float sc = L / (stRSr[gi] + EPSF);
        scalew[gi] = sc;
        const float4 p = P1[gi];
        sRow[t] = make_float4(p.x, p.y, p.z, sc);
        stRSz[gi] = 0.0f; stUz[gi] = 0.0f;        // zero next accumulation parity
    }
    __syncthreads();

    const int col = batch * MM + cg * 256 + t;
    const float4 q = P2[col];
    float s = 0.0f, tt = 0.0f;
#pragma unroll 8
    for (int ii = 0; ii < CH; ++ii) {
        const float4 a = sRow[ii];
        const float dx = a.x - q.x, dy = a.y - q.y, dz = a.z - q.z;
        const float d2 = dx*dx + dy*dy + dz*dz;
        const float e = (MODE == 2) ? a.w
                                    : a.w * __builtin_amdgcn_exp2f(coef * d2);
        s += e;
        tt = fmaf(e, __builtin_amdgcn_sqrtf(d2), tt);
    }
    atomicAdd(&stS[col], s);
    atomicAdd(&stT[col], tt);
}

// ---------------- rowK: col-finalize prelude + row-partial stream ----------------
// MODE 1: general (rs at coefN with remR_{j+1}, u via e_next^4 with Pcol_j).
// MODE 2: j==8 (rs = sum remR_9, u at coefP direct).
template<int MODE>
__global__ __launch_bounds__(256) void rowK(
    const float4* __restrict__ P1, const float4* __restrict__ P2,
    const float* __restrict__ stSr, const float* __restrict__ stTr,
    float* __restrict__ stSz, float* __restrict__ stTz,
    const float* __restrict__ remRr, float* __restrict__ remRw,
    float* __restrict__ stRS, float* __restrict__ stU,
    float* __restrict__ out,
    float coefP, float coefN)
{
    __shared__ float4 sCol[CH];                   // x2,y2,z2,remR_{j+1}
    __shared__ float  sPc[CH];                    // Pcol_j
    const int chunks = MM / CH;                   // 16
    const int bpb = (NN / 256) * chunks;          // 128
    const int batch = blockIdx.x / bpb;
    const int rem   = blockIdx.x % bpb;
    const int rg    = rem / chunks;
    const int ic    = rem % chunks;
    const int t     = threadIdx.x;

    // prelude: finalize cols of this chunk (duplicated by 8 rg-blocks; identical values)
    float c = 0.0f;
    if (t < CH) {
        const int gl = batch * MM + ic * CH + t;
        const float R  = remRr[gl];
        const float s  = stSr[gl];
        const float t2 = stTr[gl];
        const float sumr = s * R;
        const float cons = fminf(R / (sumr + EPSF), 1.0f);
        const float pcol = R * cons;
        const float Rn   = fmaxf(R - sumr * cons, 0.0f);
        remRw[gl] = Rn;
        const float4 p = P2[gl];
        sCol[t] = make_float4(p.x, p.y, p.z, Rn);
        sPc[t]  = pcol;
        stSz[gl] = 0.0f; stTz[gl] = 0.0f;         // zero next accumulation parity
        if (rg == 0) c = pcol * t2;               // cost contribution (once per chunk)
    }
    if (rg == 0) {
#pragma unroll
        for (int off = 32; off > 0; off >>= 1) c += __shfl_xor(c, off, 64);
        if (t < CH && (t & 63) == 0) atomicAdd(out + batch, c);
    }
    __syncthreads();

    const int row = batch * NN + rg * 256 + t;
    const float4 p = P1[row];
    float rs = 0.0f, u = 0.0f;
#pragma unroll 8
    for (int ii = 0; ii < CH; ++ii) {
        const float4 q = sCol[ii];
        const float dx = p.x - q.x, dy = p.y - q.y, dz = p.z - q.z;
        const float d2 = dx*dx + dy*dy + dz*dz;
        if (MODE == 1) {
            const float en = __builtin_amdgcn_exp2f(coefN * d2);
            const float e2 = en * en;
            u  = fmaf(e2 * e2, sPc[ii], u);       // e_prev = e_next^4
            rs = fmaf(en, q.w, rs);
        } else {
            const float ep = __builtin_amdgcn_exp2f(coefP * d2);
            u  = fmaf(ep, sPc[ii], u);
            rs += q.w;                            // e_next = exp(0) = 1
        }
    }
    atomicAdd(&stRS[row], rs);
    atomicAdd(&stU[row], u);
}

// ---------------- finCost: cost for level 9 (no state updates) ----------------
__global__ __launch_bounds__(256) void finCost(
    const float* __restrict__ stSr, const float* __restrict__ stTr,
    const float* __restrict__ remRr, float* __restrict__ out)
{
    const int idx = blockIdx.x * 256 + threadIdx.x;
    const int batch = idx / MM;
    const float R = remRr[idx];
    const float sumr = stSr[idx] * R;
    const float cons = fminf(R / (sumr + EPSF), 1.0f);
    float c = R * cons * stTr[idx];
#pragma unroll
    for (int off = 32; off > 0; off >>= 1) c += __shfl_xor(c, off, 64);
    if ((threadIdx.x & 63) == 0) atomicAdd(out + batch, c);
}

extern "C" void kernel_launch(void* const* d_in, const int* in_sizes, int n_in,
                              void* d_out, int out_size, void* d_ws, size_t ws_size,
                              hipStream_t stream)
{
    const float* xyz1 = (const float*)d_in[0];
    const float* xyz2 = (const float*)d_in[1];
    float* out = (float*)d_out;

    const int BN = BB * NN, BM = BB * MM;
    float4* P1 = (float4*)d_ws;
    float4* P2 = P1 + BN;
    float* remL  = (float*)(P2 + BM);       // [2][BN]
    float* scale = remL + 2 * BN;           // [2][BN]
    float* remR  = scale + 2 * BN;          // [2][BM]
    float* stRS  = remR + 2 * BM;           // [2][BN]
    float* stU   = stRS + 2 * BN;           // [2][BN]
    float* stS   = stU + 2 * BN;            // [2][BM]
    float* stT   = stS + 2 * BM;            // [2][BM]

    init_kernel<<<dim3(BN / 256), dim3(256), 0, stream>>>(
        xyz1, xyz2, P1, P2, remR, stRS, stU, stS, stT, out);

    // levels: j = 7..-1 -> -(4^j), then 0.  coef = level * log2(e)
    float coef[10];
    const double lv[10] = {-16384.0, -4096.0, -1024.0, -256.0, -64.0,
                           -16.0, -4.0, -1.0, -0.25, 0.0};
    for (int i = 0; i < 10; ++i) coef[i] = (float)(lv[i] * 1.4426950408889634);

    dim3 grid(BB * 8 * (NN / CH));          // 2048
    dim3 fgrid(BM / 256);                   // 128
    dim3 blk(256);

    rowInit<<<grid, blk, 0, stream>>>(P1, P2, stRS + 1 * BN, coef[0]);

    for (int j = 0; j < 10; ++j) {
        const int p = j & 1, q = 1 - p;
        // colK(j): remL/scale read p write q; stRS/stU read q zero p; stS/stT accum p
        if (j == 0)
            colK<0><<<grid, blk, 0, stream>>>(P1, P2,
                stRS + q*BN, stU + q*BN, stRS + p*BN, stU + p*BN,
                remL + p*BN, remL + q*BN, scale + p*BN, scale + q*BN,
                stS + p*BM, stT + p*BM, coef[0]);
        else if (j == 9)
            colK<2><<<grid, blk, 0, stream>>>(P1, P2,
                stRS + q*BN, stU + q*BN, stRS + p*BN, stU + p*BN,
                remL + p*BN, remL + q*BN, scale + p*BN, scale + q*BN,
                stS + p*BM, stT + p*BM, coef[9]);
        else
            colK<1><<<grid, blk, 0, stream>>>(P1, P2,
                stRS + q*BN, stU + q*BN, stRS + p*BN, stU + p*BN,
                remL + p*BN, remL + q*BN, scale + p*BN, scale + q*BN,
                stS + p*BM, stT + p*BM, coef[j]);

        if (j < 9) {
            // rowK(j): stS/stT read p zero q; remR read p write q; stRS/stU accum p
            if (j < 8)
                rowK<1><<<grid, blk, 0, stream>>>(P1, P2,
                    stS + p*BM, stT + p*BM, stS + q*BM, stT + q*BM,
                    remR + p*BM, remR + q*BM,
                    stRS + p*BN, stU + p*BN, out, coef[j], coef[j+1]);
            else
                rowK<2><<<grid, blk, 0, stream>>>(P1, P2,
                    stS + p*BM, stT + p*BM, stS + q*BM, stT + q*BM,
                    remR + p*BM, remR + q*BM,
                    stRS + p*BN, stU + p*BN, out, coef[8], 0.0f);
        }
    }
    // level 9 cost: stS/stT parity 1, remR parity 1
    finCost<<<fgrid, blk, 0, stream>>>(stS + 1*BM, stT + 1*BM, remR + 1*BM, out);
}

// Round 9
// 583.912 us; speedup vs baseline: 3.4996x; 1.0516x over previous
//
#include <hip/hip_runtime.h>

#define BB 16
#define NN 2048
#define MM 2048
#define EPSF 1e-9f

constexpr int CH = 64;     // stream chunk length (halved: 2 outputs/thread)
// grid: BB batches x 4 groups(512 own-points) x 32 chunks = 2048 blocks

// Ping-pong state (all cross-kernel comms at dispatch boundaries; duplicate
// writers always write bit-identical values):  see R8 comment block.
//  colK(j): reads remL/scale[j%2], writes [1-j%2]; reads stRS/stU[1-j%2],
//           zeroes stRS/stU[j%2]; accumulates stS/stT[j%2]
//  rowK(j): reads stS/stT[j%2], zeroes [1-j%2]; reads remR[j%2], writes [1-j%2];
//           accumulates stRS/stU[j%2]
//  rowInit accumulates stRS[1]; init writes remR[0]=1, zeroes all partials.

// ---------------- init ----------------
__global__ __launch_bounds__(256) void init_kernel(
    const float* __restrict__ xyz1, const float* __restrict__ xyz2,
    float4* __restrict__ P1, float4* __restrict__ P2,
    float* __restrict__ remR0,
    float* __restrict__ stRS, float* __restrict__ stU,
    float* __restrict__ stS, float* __restrict__ stT,
    float* __restrict__ out)
{
    const int t = blockIdx.x * 256 + threadIdx.x;   // 0 .. BB*NN-1
    if (t < BB * NN) {
        P1[t] = make_float4(xyz1[3*t+0], xyz1[3*t+1], xyz1[3*t+2], 0.0f);
        stRS[t] = 0.0f; stRS[BB*NN + t] = 0.0f;
        stU[t]  = 0.0f; stU[BB*NN + t]  = 0.0f;
    }
    if (t < BB * MM) {
        P2[t] = make_float4(xyz2[3*t+0], xyz2[3*t+1], xyz2[3*t+2], 0.0f);
        remR0[t] = 1.0f;
        stS[t] = 0.0f; stS[BB*MM + t] = 0.0f;
        stT[t] = 0.0f; stT[BB*MM + t] = 0.0f;
    }
    if (t < BB) out[t] = 0.0f;
}

// ---------------- rowInit: stRS[1] += sum_l exp(coef0*d2) (remR=1) ----------------
__global__ __launch_bounds__(256) void rowInit(
    const float4* __restrict__ P1, const float4* __restrict__ P2,
    float* __restrict__ stRSacc, float coef)
{
    __shared__ float4 sCol[CH];
    const int chunks = MM / CH;                   // 32
    const int bpb = (NN / 512) * chunks;          // 128
    const int batch = blockIdx.x / bpb;
    const int rem   = blockIdx.x % bpb;
    const int rg    = rem / chunks;
    const int ic    = rem % chunks;
    const int t     = threadIdx.x;

    if (t < CH) sCol[t] = P2[batch * MM + ic * CH + t];
    __syncthreads();

    const int row0 = batch * NN + rg * 512 + t;
    const int row1 = row0 + 256;
    const float4 p0 = P1[row0];
    const float4 p1 = P1[row1];
    float rs0 = 0.0f, rs1 = 0.0f;
#pragma unroll 4
    for (int ii = 0; ii < CH; ++ii) {
        const float4 q = sCol[ii];
        float dx = p0.x - q.x, dy = p0.y - q.y, dz = p0.z - q.z;
        rs0 += __builtin_amdgcn_exp2f(coef * (dx*dx + dy*dy + dz*dz));
        dx = p1.x - q.x; dy = p1.y - q.y; dz = p1.z - q.z;
        rs1 += __builtin_amdgcn_exp2f(coef * (dx*dx + dy*dy + dz*dz));
    }
    atomicAdd(&stRSacc[row0], rs0);
    atomicAdd(&stRSacc[row1], rs1);
}

// ---------------- colK: row-finalize prelude + column-partial stream ----------------
// MODE 0: j==0 (remL=1). MODE 1: general. MODE 2: j==9 (coef==0 -> e=scale).
template<int MODE>
__global__ __launch_bounds__(256) void colK(
    const float4* __restrict__ P1, const float4* __restrict__ P2,
    const float* __restrict__ stRSr, const float* __restrict__ stUr,
    float* __restrict__ stRSz, float* __restrict__ stUz,
    const float* __restrict__ remLr, float* __restrict__ remLw,
    const float* __restrict__ scaler, float* __restrict__ scalew,
    float* __restrict__ stS, float* __restrict__ stT,
    float coef)
{
    __shared__ float4 sRow[CH];                   // x1,y1,z1,scale_j
    const int chunks = NN / CH;                   // 32
    const int bpb = (MM / 512) * chunks;          // 128
    const int batch = blockIdx.x / bpb;
    const int rem   = blockIdx.x % bpb;
    const int cg    = rem / chunks;
    const int ic    = rem % chunks;
    const int t     = threadIdx.x;

    // prelude: finalize rows of this chunk (duplicated by 4 cg-blocks; identical values)
    if (t < CH) {
        const int gi = batch * NN + ic * CH + t;
        float L;
        if (MODE == 0) L = 1.0f;
        else           L = fmaxf(remLr[gi] - scaler[gi] * stUr[gi], 0.0f);
        remLw[gi] = L;
        const float sc = L / (stRSr[gi] + EPSF);
        scalew[gi] = sc;
        const float4 p = P1[gi];
        sRow[t] = make_float4(p.x, p.y, p.z, sc);
        stRSz[gi] = 0.0f; stUz[gi] = 0.0f;        // zero next accumulation parity
    }
    __syncthreads();

    const int col0 = batch * MM + cg * 512 + t;
    const int col1 = col0 + 256;
    const float4 q0 = P2[col0];
    const float4 q1 = P2[col1];
    float s0 = 0.0f, t0 = 0.0f, s1 = 0.0f, t1 = 0.0f;
#pragma unroll 4
    for (int ii = 0; ii < CH; ++ii) {
        const float4 a = sRow[ii];
        float dx = a.x - q0.x, dy = a.y - q0.y, dz = a.z - q0.z;
        const float d20 = dx*dx + dy*dy + dz*dz;
        dx = a.x - q1.x; dy = a.y - q1.y; dz = a.z - q1.z;
        const float d21 = dx*dx + dy*dy + dz*dz;
        const float e0 = (MODE == 2) ? a.w : a.w * __builtin_amdgcn_exp2f(coef * d20);
        const float e1 = (MODE == 2) ? a.w : a.w * __builtin_amdgcn_exp2f(coef * d21);
        s0 += e0; s1 += e1;
        t0 = fmaf(e0, __builtin_amdgcn_sqrtf(d20), t0);
        t1 = fmaf(e1, __builtin_amdgcn_sqrtf(d21), t1);
    }
    atomicAdd(&stS[col0], s0);
    atomicAdd(&stT[col0], t0);
    atomicAdd(&stS[col1], s1);
    atomicAdd(&stT[col1], t1);
}

// ---------------- rowK: col-finalize prelude + row-partial stream ----------------
// MODE 1: general. MODE 2: j==8 (rs = sum remR_9, u at coefP direct).
template<int MODE>
__global__ __launch_bounds__(256) void rowK(
    const float4* __restrict__ P1, const float4* __restrict__ P2,
    const float* __restrict__ stSr, const float* __restrict__ stTr,
    float* __restrict__ stSz, float* __restrict__ stTz,
    const float* __restrict__ remRr, float* __restrict__ remRw,
    float* __restrict__ stRS, float* __restrict__ stU,
    float* __restrict__ out,
    float coefP, float coefN)
{
    __shared__ float4 sCol[CH];                   // x2,y2,z2,remR_{j+1}
    __shared__ float  sPc[CH];                    // Pcol_j
    const int chunks = MM / CH;                   // 32
    const int bpb = (NN / 512) * chunks;          // 128
    const int batch = blockIdx.x / bpb;
    const int rem   = blockIdx.x % bpb;
    const int rg    = rem / chunks;
    const int ic    = rem % chunks;
    const int t     = threadIdx.x;

    // prelude: finalize cols of this chunk (duplicated by 4 rg-blocks; identical values)
    float c = 0.0f;
    if (t < CH) {
        const int gl = batch * MM + ic * CH + t;
        const float R  = remRr[gl];
        const float s  = stSr[gl];
        const float t2 = stTr[gl];
        const float sumr = s * R;
        const float cons = fminf(R / (sumr + EPSF), 1.0f);
        const float pcol = R * cons;
        const float Rn   = fmaxf(R - sumr * cons, 0.0f);
        remRw[gl] = Rn;
        const float4 p = P2[gl];
        sCol[t] = make_float4(p.x, p.y, p.z, Rn);
        sPc[t]  = pcol;
        stSz[gl] = 0.0f; stTz[gl] = 0.0f;         // zero next accumulation parity
        if (rg == 0) c = pcol * t2;               // cost contribution (once per chunk)
    }
    if (rg == 0) {
#pragma unroll
        for (int off = 32; off > 0; off >>= 1) c += __shfl_xor(c, off, 64);
        if (t < CH && (t & 63) == 0) atomicAdd(out + batch, c);
    }
    __syncthreads();

    const int row0 = batch * NN + rg * 512 + t;
    const int row1 = row0 + 256;
    const float4 p0 = P1[row0];
    const float4 p1 = P1[row1];
    float rs0 = 0.0f, u0 = 0.0f, rs1 = 0.0f, u1 = 0.0f;
#pragma unroll 4
    for (int ii = 0; ii < CH; ++ii) {
        const float4 q = sCol[ii];
        const float pc = sPc[ii];
        float dx = p0.x - q.x, dy = p0.y - q.y, dz = p0.z - q.z;
        const float d20 = dx*dx + dy*dy + dz*dz;
        dx = p1.x - q.x; dy = p1.y - q.y; dz = p1.z - q.z;
        const float d21 = dx*dx + dy*dy + dz*dz;
        if (MODE == 1) {
            const float en0 = __builtin_amdgcn_exp2f(coefN * d20);
            const float en1 = __builtin_amdgcn_exp2f(coefN * d21);
            const float e20 = en0 * en0, e21 = en1 * en1;
            u0  = fmaf(e20 * e20, pc, u0);        // e_prev = e_next^4
            u1  = fmaf(e21 * e21, pc, u1);
            rs0 = fmaf(en0, q.w, rs0);
            rs1 = fmaf(en1, q.w, rs1);
        } else {
            u0  = fmaf(__builtin_amdgcn_exp2f(coefP * d20), pc, u0);
            u1  = fmaf(__builtin_amdgcn_exp2f(coefP * d21), pc, u1);
            rs0 += q.w;                           // e_next = exp(0) = 1
            rs1 += q.w;
        }
    }
    atomicAdd(&stRS[row0], rs0);
    atomicAdd(&stU[row0], u0);
    atomicAdd(&stRS[row1], rs1);
    atomicAdd(&stU[row1], u1);
}

// ---------------- finCost: cost for level 9 (no state updates) ----------------
__global__ __launch_bounds__(256) void finCost(
    const float* __restrict__ stSr, const float* __restrict__ stTr,
    const float* __restrict__ remRr, float* __restrict__ out)
{
    const int idx = blockIdx.x * 256 + threadIdx.x;
    const int batch = idx / MM;
    const float R = remRr[idx];
    const float sumr = stSr[idx] * R;
    const float cons = fminf(R / (sumr + EPSF), 1.0f);
    float c = R * cons * stTr[idx];
#pragma unroll
    for (int off = 32; off > 0; off >>= 1) c += __shfl_xor(c, off, 64);
    if ((threadIdx.x & 63) == 0) atomicAdd(out + batch, c);
}

extern "C" void kernel_launch(void* const* d_in, const int* in_sizes, int n_in,
                              void* d_out, int out_size, void* d_ws, size_t ws_size,
                              hipStream_t stream)
{
    const float* xyz1 = (const float*)d_in[0];
    const float* xyz2 = (const float*)d_in[1];
    float* out = (float*)d_out;

    const int BN = BB * NN, BM = BB * MM;
    float4* P1 = (float4*)d_ws;
    float4* P2 = P1 + BN;
    float* remL  = (float*)(P2 + BM);       // [2][BN]
    float* scale = remL + 2 * BN;           // [2][BN]
    float* remR  = scale + 2 * BN;          // [2][BM]
    float* stRS  = remR + 2 * BM;           // [2][BN]
    float* stU   = stRS + 2 * BN;           // [2][BN]
    float* stS   = stU + 2 * BN;            // [2][BM]
    float* stT   = stS + 2 * BM;            // [2][BM]

    init_kernel<<<dim3(BN / 256), dim3(256), 0, stream>>>(
        xyz1, xyz2, P1, P2, remR, stRS, stU, stS, stT, out);

    // levels: j = 7..-1 -> -(4^j), then 0.  coef = level * log2(e)
    float coef[10];
    const double lv[10] = {-16384.0, -4096.0, -1024.0, -256.0, -64.0,
                           -16.0, -4.0, -1.0, -0.25, 0.0};
    for (int i = 0; i < 10; ++i) coef[i] = (float)(lv[i] * 1.4426950408889634);

    dim3 grid(BB * 4 * (NN / CH));          // 16*4*32 = 2048
    dim3 fgrid(BM / 256);                   // 128
    dim3 blk(256);

    rowInit<<<grid, blk, 0, stream>>>(P1, P2, stRS + 1 * BN, coef[0]);

    for (int j = 0; j < 10; ++j) {
        const int p = j & 1, q = 1 - p;
        if (j == 0)
            colK<0><<<grid, blk, 0, stream>>>(P1, P2,
                stRS + q*BN, stU + q*BN, stRS + p*BN, stU + p*BN,
                remL + p*BN, remL + q*BN, scale + p*BN, scale + q*BN,
                stS + p*BM, stT + p*BM, coef[0]);
        else if (j == 9)
            colK<2><<<grid, blk, 0, stream>>>(P1, P2,
                stRS + q*BN, stU + q*BN, stRS + p*BN, stU + p*BN,
                remL + p*BN, remL + q*BN, scale + p*BN, scale + q*BN,
                stS + p*BM, stT + p*BM, coef[9]);
        else
            colK<1><<<grid, blk, 0, stream>>>(P1, P2,
                stRS + q*BN, stU + q*BN, stRS + p*BN, stU + p*BN,
                remL + p*BN, remL + q*BN, scale + p*BN, scale + q*BN,
                stS + p*BM, stT + p*BM, coef[j]);

        if (j < 9) {
            if (j < 8)
                rowK<1><<<grid, blk, 0, stream>>>(P1, P2,
                    stS + p*BM, stT + p*BM, stS + q*BM, stT + q*BM,
                    remR + p*BM, remR + q*BM,
                    stRS + p*BN, stU + p*BN, out, coef[j], coef[j+1]);
            else
                rowK<2><<<grid, blk, 0, stream>>>(P1, P2,
                    stS + p*BM, stT + p*BM, stS + q*BM, stT + q*BM,
                    remR + p*BM, remR + q*BM,
                    stRS + p*BN, stU + p*BN, out, coef[8], 0.0f);
        }
    }
    // level 9 cost: stS/stT parity 1, remR parity 1
    finCost<<<fgrid, blk, 0, stream>>>(stS + 1*BM, stT + 1*BM, remR + 1*BM, out);
}

// Round 10
// 566.848 us; speedup vs baseline: 3.6050x; 1.0301x over previous
//
#include <hip/hip_runtime.h>

#define BB 16
#define NN 2048
#define MM 2048
#define EPSF 1e-9f
#define SKIPT (-135.0f)   // exp2(arg) == 0 (incl. denormal flush) below this

constexpr int CH = 64;     // stream chunk length (2 outputs/thread)
// grid: BB batches x 4 groups(512 own-points) x 32 chunks = 2048 blocks

// Ping-pong state (all cross-kernel comms at dispatch boundaries; duplicate
// writers always write bit-identical values):
//  colK(j): reads remL/scale[j%2], writes [1-j%2]; reads stRS/stU[1-j%2],
//           zeroes stRS/stU[j%2]; accumulates stS/stT[j%2]
//  rowK(j): reads stS/stT[j%2], zeroes [1-j%2]; reads remR[j%2], writes [1-j%2];
//           accumulates stRS/stU[j%2]
//  rowInit accumulates stRS[1]; init writes remR[0]=1, zeroes all partials.

// ---------------- init ----------------
__global__ __launch_bounds__(256) void init_kernel(
    const float* __restrict__ xyz1, const float* __restrict__ xyz2,
    float4* __restrict__ P1, float4* __restrict__ P2,
    float* __restrict__ remR0,
    float* __restrict__ stRS, float* __restrict__ stU,
    float* __restrict__ stS, float* __restrict__ stT,
    float* __restrict__ out)
{
    const int t = blockIdx.x * 256 + threadIdx.x;   // 0 .. BB*NN-1
    if (t < BB * NN) {
        P1[t] = make_float4(xyz1[3*t+0], xyz1[3*t+1], xyz1[3*t+2], 0.0f);
        stRS[t] = 0.0f; stRS[BB*NN + t] = 0.0f;
        stU[t]  = 0.0f; stU[BB*NN + t]  = 0.0f;
    }
    if (t < BB * MM) {
        P2[t] = make_float4(xyz2[3*t+0], xyz2[3*t+1], xyz2[3*t+2], 0.0f);
        remR0[t] = 1.0f;
        stS[t] = 0.0f; stS[BB*MM + t] = 0.0f;
        stT[t] = 0.0f; stT[BB*MM + t] = 0.0f;
    }
    if (t < BB) out[t] = 0.0f;
}

// ---------------- rowInit: stRS[1] += sum_l exp(coef0*d2) (remR=1) ----------------
__global__ __launch_bounds__(256) void rowInit(
    const float4* __restrict__ P1, const float4* __restrict__ P2,
    float* __restrict__ stRSacc, float coef)
{
    __shared__ float4 sCol[CH];
    const int chunks = MM / CH;                   // 32
    const int bpb = (NN / 512) * chunks;          // 128
    const int batch = blockIdx.x / bpb;
    const int rem   = blockIdx.x % bpb;
    const int rg    = rem / chunks;
    const int ic    = rem % chunks;
    const int t     = threadIdx.x;

    if (t < CH) sCol[t] = P2[batch * MM + ic * CH + t];
    __syncthreads();

    const int row0 = batch * NN + rg * 512 + t;
    const int row1 = row0 + 256;
    const float4 p0 = P1[row0];
    const float4 p1 = P1[row1];
    float rs0 = 0.0f, rs1 = 0.0f;
#pragma unroll 4
    for (int ii = 0; ii < CH; ++ii) {
        const float4 q = sCol[ii];
        float dx = p0.x - q.x, dy = p0.y - q.y, dz = p0.z - q.z;
        const float g0 = coef * (dx*dx + dy*dy + dz*dz);
        dx = p1.x - q.x; dy = p1.y - q.y; dz = p1.z - q.z;
        const float g1 = coef * (dx*dx + dy*dy + dz*dz);
        if (__ballot((g0 > SKIPT) || (g1 > SKIPT))) {
            rs0 += __builtin_amdgcn_exp2f(g0);
            rs1 += __builtin_amdgcn_exp2f(g1);
        }
    }
    atomicAdd(&stRSacc[row0], rs0);
    atomicAdd(&stRSacc[row1], rs1);
}

// ---------------- colK: row-finalize prelude + column-partial stream ----------------
// MODE 0: j==0 (remL=1). MODE 1: general. MODE 2: j==9 (coef==0 -> e=scale).
// SPARSE: wave-skip exp/sqrt when all lanes underflow (early levels only).
template<int MODE, bool SPARSE>
__global__ __launch_bounds__(256) void colK(
    const float4* __restrict__ P1, const float4* __restrict__ P2,
    const float* __restrict__ stRSr, const float* __restrict__ stUr,
    float* __restrict__ stRSz, float* __restrict__ stUz,
    const float* __restrict__ remLr, float* __restrict__ remLw,
    const float* __restrict__ scaler, float* __restrict__ scalew,
    float* __restrict__ stS, float* __restrict__ stT,
    float coef)
{
    __shared__ float4 sRow[CH];                   // x1,y1,z1,scale_j
    const int chunks = NN / CH;                   // 32
    const int bpb = (MM / 512) * chunks;          // 128
    const int batch = blockIdx.x / bpb;
    const int rem   = blockIdx.x % bpb;
    const int cg    = rem / chunks;
    const int ic    = rem % chunks;
    const int t     = threadIdx.x;

    // prelude: finalize rows of this chunk (duplicated by 4 cg-blocks; identical values)
    if (t < CH) {
        const int gi = batch * NN + ic * CH + t;
        float L;
        if (MODE == 0) L = 1.0f;
        else           L = fmaxf(remLr[gi] - scaler[gi] * stUr[gi], 0.0f);
        remLw[gi] = L;
        const float sc = L / (stRSr[gi] + EPSF);
        scalew[gi] = sc;
        const float4 p = P1[gi];
        sRow[t] = make_float4(p.x, p.y, p.z, sc);
        stRSz[gi] = 0.0f; stUz[gi] = 0.0f;        // zero next accumulation parity
    }
    __syncthreads();

    const int col0 = batch * MM + cg * 512 + t;
    const int col1 = col0 + 256;
    const float4 q0 = P2[col0];
    const float4 q1 = P2[col1];
    float s0 = 0.0f, t0 = 0.0f, s1 = 0.0f, t1 = 0.0f;
#pragma unroll 4
    for (int ii = 0; ii < CH; ++ii) {
        const float4 a = sRow[ii];
        float dx = a.x - q0.x, dy = a.y - q0.y, dz = a.z - q0.z;
        const float d20 = dx*dx + dy*dy + dz*dz;
        dx = a.x - q1.x; dy = a.y - q1.y; dz = a.z - q1.z;
        const float d21 = dx*dx + dy*dy + dz*dz;
        if (SPARSE) {
            const float g0 = coef * d20, g1 = coef * d21;
            if (__ballot((g0 > SKIPT) || (g1 > SKIPT))) {
                const float e0 = a.w * __builtin_amdgcn_exp2f(g0);
                const float e1 = a.w * __builtin_amdgcn_exp2f(g1);
                s0 += e0; s1 += e1;
                t0 = fmaf(e0, __builtin_amdgcn_sqrtf(d20), t0);
                t1 = fmaf(e1, __builtin_amdgcn_sqrtf(d21), t1);
            }
        } else {
            const float e0 = (MODE == 2) ? a.w : a.w * __builtin_amdgcn_exp2f(coef * d20);
            const float e1 = (MODE == 2) ? a.w : a.w * __builtin_amdgcn_exp2f(coef * d21);
            s0 += e0; s1 += e1;
            t0 = fmaf(e0, __builtin_amdgcn_sqrtf(d20), t0);
            t1 = fmaf(e1, __builtin_amdgcn_sqrtf(d21), t1);
        }
    }
    atomicAdd(&stS[col0], s0);
    atomicAdd(&stT[col0], t0);
    atomicAdd(&stS[col1], s1);
    atomicAdd(&stT[col1], t1);
}

// ---------------- rowK: col-finalize prelude + row-partial stream ----------------
// MODE 1: general. MODE 2: j==8 (rs = sum remR_9, u at coefP direct).
template<int MODE, bool SPARSE>
__global__ __launch_bounds__(256) void rowK(
    const float4* __restrict__ P1, const float4* __restrict__ P2,
    const float* __restrict__ stSr, const float* __restrict__ stTr,
    float* __restrict__ stSz, float* __restrict__ stTz,
    const float* __restrict__ remRr, float* __restrict__ remRw,
    float* __restrict__ stRS, float* __restrict__ stU,
    float* __restrict__ out,
    float coefP, float coefN)
{
    __shared__ float4 sCol[CH];                   // x2,y2,z2,remR_{j+1}
    __shared__ float  sPc[CH];                    // Pcol_j
    const int chunks = MM / CH;                   // 32
    const int bpb = (NN / 512) * chunks;          // 128
    const int batch = blockIdx.x / bpb;
    const int rem   = blockIdx.x % bpb;
    const int rg    = rem / chunks;
    const int ic    = rem % chunks;
    const int t     = threadIdx.x;

    // prelude: finalize cols of this chunk (duplicated by 4 rg-blocks; identical values)
    float c = 0.0f;
    if (t < CH) {
        const int gl = batch * MM + ic * CH + t;
        const float R  = remRr[gl];
        const float s  = stSr[gl];
        const float t2 = stTr[gl];
        const float sumr = s * R;
        const float cons = fminf(R / (sumr + EPSF), 1.0f);
        const float pcol = R * cons;
        const float Rn   = fmaxf(R - sumr * cons, 0.0f);
        remRw[gl] = Rn;
        const float4 p = P2[gl];
        sCol[t] = make_float4(p.x, p.y, p.z, Rn);
        sPc[t]  = pcol;
        stSz[gl] = 0.0f; stTz[gl] = 0.0f;         // zero next accumulation parity
        if (rg == 0) c = pcol * t2;               // cost contribution (once per chunk)
    }
    if (rg == 0) {
#pragma unroll
        for (int off = 32; off > 0; off >>= 1) c += __shfl_xor(c, off, 64);
        if (t < CH && (t & 63) == 0) atomicAdd(out + batch, c);
    }
    __syncthreads();

    const int row0 = batch * NN + rg * 512 + t;
    const int row1 = row0 + 256;
    const float4 p0 = P1[row0];
    const float4 p1 = P1[row1];
    float rs0 = 0.0f, u0 = 0.0f, rs1 = 0.0f, u1 = 0.0f;
#pragma unroll 4
    for (int ii = 0; ii < CH; ++ii) {
        const float4 q = sCol[ii];
        const float pc = sPc[ii];
        float dx = p0.x - q.x, dy = p0.y - q.y, dz = p0.z - q.z;
        const float d20 = dx*dx + dy*dy + dz*dz;
        dx = p1.x - q.x; dy = p1.y - q.y; dz = p1.z - q.z;
        const float d21 = dx*dx + dy*dy + dz*dz;
        if (MODE == 1) {
            if (SPARSE) {
                const float g0 = coefN * d20, g1 = coefN * d21;
                if (__ballot((g0 > SKIPT) || (g1 > SKIPT))) {
                    const float en0 = __builtin_amdgcn_exp2f(g0);
                    const float en1 = __builtin_amdgcn_exp2f(g1);
                    const float e20 = en0 * en0, e21 = en1 * en1;
                    u0  = fmaf(e20 * e20, pc, u0);    // e_prev = e_next^4
                    u1  = fmaf(e21 * e21, pc, u1);
                    rs0 = fmaf(en0, q.w, rs0);
                    rs1 = fmaf(en1, q.w, rs1);
                }
            } else {
                const float en0 = __builtin_amdgcn_exp2f(coefN * d20);
                const float en1 = __builtin_amdgcn_exp2f(coefN * d21);
                const float e20 = en0 * en0, e21 = en1 * en1;
                u0  = fmaf(e20 * e20, pc, u0);        // e_prev = e_next^4
                u1  = fmaf(e21 * e21, pc, u1);
                rs0 = fmaf(en0, q.w, rs0);
                rs1 = fmaf(en1, q.w, rs1);
            }
        } else {
            u0  = fmaf(__builtin_amdgcn_exp2f(coefP * d20), pc, u0);
            u1  = fmaf(__builtin_amdgcn_exp2f(coefP * d21), pc, u1);
            rs0 += q.w;                           // e_next = exp(0) = 1
            rs1 += q.w;
        }
    }
    atomicAdd(&stRS[row0], rs0);
    atomicAdd(&stU[row0], u0);
    atomicAdd(&stRS[row1], rs1);
    atomicAdd(&stU[row1], u1);
}

// ---------------- finCost: cost for level 9 (no state updates) ----------------
__global__ __launch_bounds__(256) void finCost(
    const float* __restrict__ stSr, const float* __restrict__ stTr,
    const float* __restrict__ remRr, float* __restrict__ out)
{
    const int idx = blockIdx.x * 256 + threadIdx.x;
    const int batch = idx / MM;
    const float R = remRr[idx];
    const float sumr = stSr[idx] * R;
    const float cons = fminf(R / (sumr + EPSF), 1.0f);
    float c = R * cons * stTr[idx];
#pragma unroll
    for (int off = 32; off > 0; off >>= 1) c += __shfl_xor(c, off, 64);
    if ((threadIdx.x & 63) == 0) atomicAdd(out + batch, c);
}

extern "C" void kernel_launch(void* const* d_in, const int* in_sizes, int n_in,
                              void* d_out, int out_size, void* d_ws, size_t ws_size,
                              hipStream_t stream)
{
    const float* xyz1 = (const float*)d_in[0];
    const float* xyz2 = (const float*)d_in[1];
    float* out = (float*)d_out;

    const int BN = BB * NN, BM = BB * MM;
    float4* P1 = (float4*)d_ws;
    float4* P2 = P1 + BN;
    float* remL  = (float*)(P2 + BM);       // [2][BN]
    float* scale = remL + 2 * BN;           // [2][BN]
    float* remR  = scale + 2 * BN;          // [2][BM]
    float* stRS  = remR + 2 * BM;           // [2][BN]
    float* stU   = stRS + 2 * BN;           // [2][BN]
    float* stS   = stU + 2 * BN;            // [2][BM]
    float* stT   = stS + 2 * BM;            // [2][BM]

    init_kernel<<<dim3(BN / 256), dim3(256), 0, stream>>>(
        xyz1, xyz2, P1, P2, remR, stRS, stU, stS, stT, out);

    // levels: j = 7..-1 -> -(4^j), then 0.  coef = level * log2(e)
    float coef[10];
    const double lv[10] = {-16384.0, -4096.0, -1024.0, -256.0, -64.0,
                           -16.0, -4.0, -1.0, -0.25, 0.0};
    for (int i = 0; i < 10; ++i) coef[i] = (float)(lv[i] * 1.4426950408889634);

    dim3 grid(BB * 4 * (NN / CH));          // 16*4*32 = 2048
    dim3 fgrid(BM / 256);                   // 128
    dim3 blk(256);

    rowInit<<<grid, blk, 0, stream>>>(P1, P2, stRS + 1 * BN, coef[0]);

    for (int j = 0; j < 10; ++j) {
        const int p = j & 1, q = 1 - p;
        // colK(j): SPARSE for j<=3 (levels -16384..-256)
        if (j == 0)
            colK<0, true><<<grid, blk, 0, stream>>>(P1, P2,
                stRS + q*BN, stU + q*BN, stRS + p*BN, stU + p*BN,
                remL + p*BN, remL + q*BN, scale + p*BN, scale + q*BN,
                stS + p*BM, stT + p*BM, coef[0]);
        else if (j <= 3)
            colK<1, true><<<grid, blk, 0, stream>>>(P1, P2,
                stRS + q*BN, stU + q*BN, stRS + p*BN, stU + p*BN,
                remL + p*BN, remL + q*BN, scale + p*BN, scale + q*BN,
                stS + p*BM, stT + p*BM, coef[j]);
        else if (j == 9)
            colK<2, false><<<grid, blk, 0, stream>>>(P1, P2,
                stRS + q*BN, stU + q*BN, stRS + p*BN, stU + p*BN,
                remL + p*BN, remL + q*BN, scale + p*BN, scale + q*BN,
                stS + p*BM, stT + p*BM, coef[9]);
        else
            colK<1, false><<<grid, blk, 0, stream>>>(P1, P2,
                stRS + q*BN, stU + q*BN, stRS + p*BN, stU + p*BN,
                remL + p*BN, remL + q*BN, scale + p*BN, scale + q*BN,
                stS + p*BM, stT + p*BM, coef[j]);

        if (j < 9) {
            // rowK(j): SPARSE for j<=2 (coefN = coef[1..3])
            if (j <= 2)
                rowK<1, true><<<grid, blk, 0, stream>>>(P1, P2,
                    stS + p*BM, stT + p*BM, stS + q*BM, stT + q*BM,
                    remR + p*BM, remR + q*BM,
                    stRS + p*BN, stU + p*BN, out, coef[j], coef[j+1]);
            else if (j < 8)
                rowK<1, false><<<grid, blk, 0, stream>>>(P1, P2,
                    stS + p*BM, stT + p*BM, stS + q*BM, stT + q*BM,
                    remR + p*BM, remR + q*BM,
                    stRS + p*BN, stU + p*BN, out, coef[j], coef[j+1]);
            else
                rowK<2, false><<<grid, blk, 0, stream>>>(P1, P2,
                    stS + p*BM, stT + p*BM, stS + q*BM, stT + q*BM,
                    remR + p*BM, remR + q*BM,
                    stRS + p*BN, stU + p*BN, out, coef[8], 0.0f);
        }
    }
    // level 9 cost: stS/stT parity 1, remR parity 1
    finCost<<<fgrid, blk, 0, stream>>>(stS + 1*BM, stT + 1*BM, remR + 1*BM, out);
}